// Round 3
// baseline (8388.348 us; speedup 1.0000x reference)
//
#include <hip/hip_runtime.h>
#include <hip/hip_bf16.h>

#define BB 128
#define TT 256
#define VV 128
#define HH 1024
#define NG 4096   // 4*H gate columns (permuted: n = hc*4 + kg)
#define KK 1152   // V + H fused reduction dim

typedef unsigned short ushort_t;
typedef short bf16x8 __attribute__((ext_vector_type(8)));
typedef float f32x4 __attribute__((ext_vector_type(4)));

__device__ __forceinline__ ushort_t f2bf(float f) {
  unsigned u = __builtin_bit_cast(unsigned, f);
  u += 0x7fffu + ((u >> 16) & 1u);   // RTNE
  return (ushort_t)(u >> 16);
}

__device__ __forceinline__ uint4 pack8(const float* p) {
  float4 a = *(const float4*)p;
  float4 b = *(const float4*)(p + 4);
  uint4 r;
  r.x = (unsigned)f2bf(a.x) | ((unsigned)f2bf(a.y) << 16);
  r.y = (unsigned)f2bf(a.z) | ((unsigned)f2bf(a.w) << 16);
  r.z = (unsigned)f2bf(b.x) | ((unsigned)f2bf(b.y) << 16);
  r.w = (unsigned)f2bf(b.z) | ((unsigned)f2bf(b.w) << 16);
  return r;
}

__device__ __forceinline__ f32x4 MFMA(bf16x8 a, bf16x8 b, f32x4 c) {
  return __builtin_amdgcn_mfma_f32_16x16x32_bf16(a, b, c, 0, 0, 0);
}

// LDS h-panel addressing: row stride 2048 B, XOR-swizzle bits 4-6 by row&7
// (breaks the 16-way bank conflict of the stride-2048 fragment reads -> 2-way)
__device__ __forceinline__ ushort_t* aswz(ushort_t* As, int row, int kelem) {
  int byte = (row << 11) + ((kelem << 1) ^ ((row & 7) << 4));
  return (ushort_t*)((char*)As + byte);
}

// ---- grid barrier: generation flag, acq_rel arrival, acquire spin ----------
__device__ __forceinline__ void gbar(unsigned* bar, unsigned target) {
  __syncthreads();                    // drains all waves' vmem before arrival
  if (threadIdx.x == 0) {
    __threadfence();                  // release: write back L2 -> LLC
    unsigned arr = __hip_atomic_fetch_add(bar, 1u, __ATOMIC_ACQ_REL,
                                          __HIP_MEMORY_SCOPE_AGENT);
    if (arr == 255u) {
      __hip_atomic_store(bar, 0u, __ATOMIC_RELAXED, __HIP_MEMORY_SCOPE_AGENT);
      __hip_atomic_store(bar + 1, target, __ATOMIC_RELEASE,
                         __HIP_MEMORY_SCOPE_AGENT);
    } else {
      while (__hip_atomic_load(bar + 1, __ATOMIC_ACQUIRE,
                               __HIP_MEMORY_SCOPE_AGENT) != target)
        __builtin_amdgcn_s_sleep(1);
    }
    __threadfence();                  // acquire: invalidate L1/L2
  }
  __syncthreads();
}

// ---------------- init: h0 bf16, Wl->bf16, bias = bx+bh (permuted), barrier --
__global__ void init_misc(const float* __restrict__ h_in, const float* __restrict__ Wl,
                          const float* __restrict__ bx, const float* __restrict__ bh,
                          ushort_t* __restrict__ hbf0, ushort_t* __restrict__ wlbf,
                          float* __restrict__ bias, unsigned* __restrict__ bar) {
  int i = blockIdx.x * blockDim.x + threadIdx.x;   // grid covers 131072 exactly
  hbf0[i] = f2bf(h_in[i]);
  wlbf[i] = f2bf(Wl[i]);
  if (i < NG) {
    int kg = i & 3, hc = i >> 2;
    bias[i] = bx[kg * HH + hc] + bh[kg * HH + hc];
  }
  if (i < 2) bar[i] = 0u;
}

// ------------- build WcombT[n][k] bf16, n = hc*4+kg, k = [x(128) | h(1024)] --
__global__ void build_wcombT(const float* __restrict__ Wx, const float* __restrict__ Wh,
                             ushort_t* __restrict__ wcombT) {
  __shared__ float tile[32][33];
  const int k0 = blockIdx.x * 32, hc0 = blockIdx.y * 32, kg = blockIdx.z;
  const int tid = threadIdx.x;
#pragma unroll
  for (int p = 0; p < 4; ++p) {
    int kk = (tid >> 5) + p * 8, hh = tid & 31;
    int k = k0 + kk, hc = hc0 + hh;
    float v = (k < VV) ? Wx[kg * VV * HH + k * HH + hc]
                       : Wh[kg * HH * HH + (k - VV) * HH + hc];
    tile[kk][hh] = v;
  }
  __syncthreads();
#pragma unroll
  for (int p = 0; p < 4; ++p) {
    int hh = (tid >> 5) + p * 8, kk = tid & 31;
    int n = (hc0 + hh) * 4 + kg;
    wcombT[n * KK + k0 + kk] = f2bf(tile[kk][hh]);
  }
}

// ---------------- persistent LSTM: all 256 timesteps, weights in VGPRs ------
// grid 256 (mb = blk&3 -> 32 batch rows, nb = blk>>2 -> 64 gate cols), 4 waves
__global__ __launch_bounds__(256, 1) void lstm_persist(
    const float* __restrict__ x, const ushort_t* __restrict__ wcombT,
    const float* __restrict__ bias, ushort_t* __restrict__ hping,
    ushort_t* __restrict__ outs, const float* __restrict__ c_in,
    float* __restrict__ hout, float* __restrict__ cout,
    unsigned* __restrict__ bar) {
  __shared__ __align__(16) ushort_t As[32 * 1024];   // 65,536 B (h panel only)

  const int tid = threadIdx.x;
  const int b0 = (blockIdx.x & 3) * 32;
  const int n0 = (blockIdx.x >> 2) * 64;
  const int wave = tid >> 6, lane = tid & 63;
  const int wm = wave >> 1, wn = wave & 1;
  const int c15 = lane & 15, q = lane >> 4;
  const int kg = lane & 3;
  const bool isg = (kg == 2);
  const int arow = wm * 16 + c15;                  // A-fragment row (0..31)
  const int rbase = b0 + wm * 16 + q * 4;
  const int hu0 = (n0 >> 2) + wn * 8 + (c15 >> 2); // + j*4

  // ---- one-time: B fragments into registers (288 VGPRs) ----
  bf16x8 breg[36][2];
#pragma unroll
  for (int ks = 0; ks < 36; ++ks)
#pragma unroll
    for (int j = 0; j < 2; ++j)
      breg[ks][j] = *(const bf16x8*)(wcombT +
          (size_t)(n0 + wn * 32 + j * 16 + c15) * KK + ks * 32 + q * 8);

  float biasr[2];
#pragma unroll
  for (int j = 0; j < 2; ++j)
    biasr[j] = bias[n0 + wn * 32 + j * 16 + c15];

  // ---- one-time: c state into registers (valid on kg==0 lanes) ----
  float cr[2][4];
#pragma unroll
  for (int j = 0; j < 2; ++j)
#pragma unroll
    for (int r = 0; r < 4; ++r)
      cr[j][r] = c_in[(size_t)(rbase + r) * HH + hu0 + j * 4];

  const float* xlane = x + (size_t)(b0 + arow) * (TT * VV) + q * 8;

  for (int t = 0; t < TT; ++t) {
    const ushort_t* hc_ = hping + (size_t)(t & 1) * BB * HH;
    ushort_t* hn_ = hping + (size_t)((t + 1) & 1) * BB * HH;

    // ---- per-lane x fragments (fp32 -> bf16, rows are lane-fixed) ----
    bf16x8 xr[4];
#pragma unroll
    for (int ks = 0; ks < 4; ++ks)
      xr[ks] = __builtin_bit_cast(bf16x8, pack8(xlane + t * VV + ks * 32));

    // ---- stage h panel into LDS (swizzled) ----
#pragma unroll
    for (int i = 0; i < 16; ++i) {
      int idx = i * 256 + tid;
      int row = idx >> 7, ko = (idx & 127) * 8;
      *(uint4*)aswz(As, row, ko) =
          *(const uint4*)(hc_ + (size_t)(b0 + row) * HH + ko);
    }
    __syncthreads();

    // ---- MFMA K-loop: 4 independent accumulator chains ----
    f32x4 a0e = {0.f,0.f,0.f,0.f}, a0o = {0.f,0.f,0.f,0.f};
    f32x4 a1e = {0.f,0.f,0.f,0.f}, a1o = {0.f,0.f,0.f,0.f};
#pragma unroll
    for (int ks = 0; ks < 4; ks += 2) {       // x part from registers
      a0e = MFMA(xr[ks], breg[ks][0], a0e);
      a1e = MFMA(xr[ks], breg[ks][1], a1e);
      a0o = MFMA(xr[ks + 1], breg[ks + 1][0], a0o);
      a1o = MFMA(xr[ks + 1], breg[ks + 1][1], a1o);
    }
#pragma unroll
    for (int hs = 0; hs < 32; hs += 2) {      // h part from LDS
      bf16x8 af0 = *(const bf16x8*)aswz(As, arow, hs * 32 + q * 8);
      bf16x8 af1 = *(const bf16x8*)aswz(As, arow, (hs + 1) * 32 + q * 8);
      a0e = MFMA(af0, breg[4 + hs][0], a0e);
      a1e = MFMA(af0, breg[4 + hs][1], a1e);
      a0o = MFMA(af1, breg[5 + hs][0], a0o);
      a1o = MFMA(af1, breg[5 + hs][1], a1o);
    }
    f32x4 g0 = a0e + a0o, g1 = a1e + a1o;

    // ---- pointwise LSTM in registers (4 gates live in 4-lane groups) ----
    const bool last = (t == TT - 1);
#pragma unroll
    for (int j = 0; j < 2; ++j) {
      f32x4 gj = j ? g1 : g0;
#pragma unroll
      for (int r = 0; r < 4; ++r) {
        float pre = gj[r] + biasr[j];
        float sx = isg ? pre + pre : pre;
        float sg = 1.f / (1.f + expf(-sx));
        float a = isg ? sg + sg - 1.f : sg;     // own gate activation
        float fv = __shfl_xor(a, 1);
        float gv = __shfl_xor(a, 2);
        float ov = __shfl_xor(fv, 2);
        float cn = fv * cr[j][r] + a * gv;      // valid on kg==0 lanes
        cr[j][r] = cn;
        float hn = ov * tanhf(cn);
        if (kg == 0) {
          int b = rbase + r, hu = hu0 + j * 4;
          hn_[(size_t)b * HH + hu] = f2bf(hn);
          outs[((size_t)b * TT + t) * HH + hu] = f2bf(ov);  // o gate collected
          if (last) {
            hout[(size_t)b * HH + hu] = hn;
            cout[(size_t)b * HH + hu] = cn;
          }
        }
      }
    }

    if (t < TT - 1) gbar(bar, (unsigned)(t + 1));
  }
}

// ---------------- logits = outs(bf16) @ Wl^T + bl ---------------------------
// grid 512, 256 threads (waves 2x2), WG tile 64(M) x 128(N=V)
__global__ __launch_bounds__(256) void logits_gemm(
    const ushort_t* __restrict__ outs, const ushort_t* __restrict__ wlbf,
    const float* __restrict__ bl, float* __restrict__ out) {
  __shared__ __align__(16) ushort_t Asl[2][64][72];
  __shared__ __align__(16) ushort_t Bsl[2][128][72];
  const int tid = threadIdx.x;
  const int m0 = blockIdx.x * 64;
  const int wave = tid >> 6, lane = tid & 63;
  const int wm = wave >> 1, wn = wave & 1;
  const int ar = tid >> 2, ak = (tid & 3) * 16;
  const int br = tid >> 1, bk = (tid & 1) * 32;

  f32x4 acc[2][4];
#pragma unroll
  for (int i = 0; i < 2; ++i)
#pragma unroll
    for (int j = 0; j < 4; ++j) acc[i][j] = {0.f, 0.f, 0.f, 0.f};

  const ushort_t* pa = outs + (size_t)(m0 + ar) * HH + ak;
  uint4 av0 = *(const uint4*)pa, av1 = *(const uint4*)(pa + 8);
  const ushort_t* pb = wlbf + (size_t)br * HH + bk;
  uint4 bv0 = *(const uint4*)pb, bv1 = *(const uint4*)(pb + 8);
  uint4 bv2 = *(const uint4*)(pb + 16), bv3 = *(const uint4*)(pb + 24);

  int buf = 0;
  for (int s = 0; s < 16; ++s) {
    *(uint4*)&Asl[buf][ar][ak] = av0;
    *(uint4*)&Asl[buf][ar][ak + 8] = av1;
    *(uint4*)&Bsl[buf][br][bk] = bv0;
    *(uint4*)&Bsl[buf][br][bk + 8] = bv1;
    *(uint4*)&Bsl[buf][br][bk + 16] = bv2;
    *(uint4*)&Bsl[buf][br][bk + 24] = bv3;
    if (s < 15) {
      int k0 = (s + 1) * 64;
      const ushort_t* qa = outs + (size_t)(m0 + ar) * HH + k0 + ak;
      av0 = *(const uint4*)qa; av1 = *(const uint4*)(qa + 8);
      const ushort_t* qb = wlbf + (size_t)br * HH + k0 + bk;
      bv0 = *(const uint4*)qb; bv1 = *(const uint4*)(qb + 8);
      bv2 = *(const uint4*)(qb + 16); bv3 = *(const uint4*)(qb + 24);
    }
    __syncthreads();
#pragma unroll
    for (int kk = 0; kk < 64; kk += 32) {
      int koff = kk + (lane >> 4) * 8;
      bf16x8 a0 = *(const bf16x8*)&Asl[buf][wm * 32 + (lane & 15)][koff];
      bf16x8 a1 = *(const bf16x8*)&Asl[buf][wm * 32 + 16 + (lane & 15)][koff];
      bf16x8 b0 = *(const bf16x8*)&Bsl[buf][wn * 64 + (lane & 15)][koff];
      bf16x8 b1 = *(const bf16x8*)&Bsl[buf][wn * 64 + 16 + (lane & 15)][koff];
      bf16x8 b2 = *(const bf16x8*)&Bsl[buf][wn * 64 + 32 + (lane & 15)][koff];
      bf16x8 b3 = *(const bf16x8*)&Bsl[buf][wn * 64 + 48 + (lane & 15)][koff];
      acc[0][0] = MFMA(a0, b0, acc[0][0]);
      acc[0][1] = MFMA(a0, b1, acc[0][1]);
      acc[0][2] = MFMA(a0, b2, acc[0][2]);
      acc[0][3] = MFMA(a0, b3, acc[0][3]);
      acc[1][0] = MFMA(a1, b0, acc[1][0]);
      acc[1][1] = MFMA(a1, b1, acc[1][1]);
      acc[1][2] = MFMA(a1, b2, acc[1][2]);
      acc[1][3] = MFMA(a1, b3, acc[1][3]);
    }
    buf ^= 1;
  }
#pragma unroll
  for (int i = 0; i < 2; ++i)
#pragma unroll
    for (int j = 0; j < 4; ++j)
#pragma unroll
      for (int r = 0; r < 4; ++r) {
        int m = m0 + wm * 32 + i * 16 + (lane >> 4) * 4 + r;
        int v = wn * 64 + j * 16 + (lane & 15);
        out[(size_t)m * VV + v] = acc[i][j][r] + bl[v];
      }
}

// ----------------------------------------------------------------------------
extern "C" void kernel_launch(void* const* d_in, const int* in_sizes, int n_in,
                              void* d_out, int out_size, void* d_ws, size_t ws_size,
                              hipStream_t stream) {
  const float* x    = (const float*)d_in[0];
  const float* h_in = (const float*)d_in[1];
  const float* c_in = (const float*)d_in[2];
  const float* Wx   = (const float*)d_in[3];
  const float* Wh   = (const float*)d_in[4];
  const float* bx   = (const float*)d_in[5];
  const float* bh   = (const float*)d_in[6];
  const float* Wl   = (const float*)d_in[7];
  const float* bl   = (const float*)d_in[8];

  char* ws = (char*)d_ws;
  size_t off = 0;
  ushort_t* wcombT = (ushort_t*)(ws + off); off += (size_t)NG * KK * 2;        // 9.4 MB
  ushort_t* outs   = (ushort_t*)(ws + off); off += (size_t)BB * TT * HH * 2;   // 67 MB
  ushort_t* hbf    = (ushort_t*)(ws + off); off += (size_t)2 * BB * HH * 2;    // ping-pong
  float*    bias   = (float*)(ws + off);    off += (size_t)NG * 4;
  ushort_t* wlbf   = (ushort_t*)(ws + off); off += (size_t)VV * HH * 2;
  off = (off + 127) & ~(size_t)127;
  unsigned* bar    = (unsigned*)(ws + off); off += 128;

  float* out  = (float*)d_out;
  float* hout = out + (size_t)BB * TT * VV;
  float* cout = hout + (size_t)BB * HH;

  init_misc<<<dim3(512), dim3(256), 0, stream>>>(h_in, Wl, bx, bh,
                                                 hbf, wlbf, bias, bar);
  build_wcombT<<<dim3(36, 32, 4), dim3(256), 0, stream>>>(Wx, Wh, wcombT);

  {
    void* kargs[] = {(void*)&x, (void*)&wcombT, (void*)&bias, (void*)&hbf,
                     (void*)&outs, (void*)&c_in, (void*)&hout, (void*)&cout,
                     (void*)&bar};
    hipError_t ce = hipLaunchCooperativeKernel((const void*)lstm_persist,
                                               dim3(256), dim3(256), kargs, 0,
                                               stream);
    if (ce != hipSuccess) {
      (void)hipGetLastError();  // clear sticky error; fall back to plain launch
      // grid == CU count, 1 block/CU -> co-resident in practice; barrier works
      lstm_persist<<<dim3(256), dim3(256), 0, stream>>>(
          x, wcombT, bias, hbf, outs, c_in, hout, cout, bar);
    }
  }

  logits_gemm<<<dim3(512), dim3(256), 0, stream>>>(outs, wlbf, bl, out);
}

// Round 4
// 2892.389 us; speedup vs baseline: 2.9001x; 2.9001x over previous
//
#include <hip/hip_runtime.h>
#include <hip/hip_bf16.h>

#define BB 128
#define TT 256
#define VV 128
#define HH 1024
#define NG 4096   // 4*H gate columns (permuted: n = hc*4 + kg)
#define KK 1152   // V + H fused reduction dim

typedef unsigned short ushort_t;
typedef short bf16x8 __attribute__((ext_vector_type(8)));
typedef float f32x4 __attribute__((ext_vector_type(4)));

__device__ __forceinline__ ushort_t f2bf(float f) {
  unsigned u = __builtin_bit_cast(unsigned, f);
  u += 0x7fffu + ((u >> 16) & 1u);   // RTNE
  return (ushort_t)(u >> 16);
}

__device__ __forceinline__ uint4 pack8(const float* p) {
  float4 a = *(const float4*)p;
  float4 b = *(const float4*)(p + 4);
  uint4 r;
  r.x = (unsigned)f2bf(a.x) | ((unsigned)f2bf(a.y) << 16);
  r.y = (unsigned)f2bf(a.z) | ((unsigned)f2bf(a.w) << 16);
  r.z = (unsigned)f2bf(b.x) | ((unsigned)f2bf(b.y) << 16);
  r.w = (unsigned)f2bf(b.z) | ((unsigned)f2bf(b.w) << 16);
  return r;
}

__device__ __forceinline__ f32x4 MFMA(bf16x8 a, bf16x8 b, f32x4 c) {
  return __builtin_amdgcn_mfma_f32_16x16x32_bf16(a, b, c, 0, 0, 0);
}

// LDS h-panel addressing: row stride 2048 B, XOR-swizzle bits 4-6 by row&7
__device__ __forceinline__ ushort_t* aswz(ushort_t* As, int row, int kelem) {
  int byte = (row << 11) + ((kelem << 1) ^ ((row & 7) << 4));
  return (ushort_t*)((char*)As + byte);
}

// ---- hierarchical grid barrier: monotonic counters, relaxed spins, ---------
// ---- exactly one acquire fence (buffer_inv) per block per step -------------
// bar[0]: root; bar[32*(1+g)]: sub-counter g; bar[32*(9+g)]: group flag g
__device__ __forceinline__ void gbar(unsigned* bar, unsigned gen, int grp) {
  __syncthreads();   // compiler emits vmcnt(0): all waves' WT h-stores at LLC
  if (threadIdx.x == 0) {
    unsigned* sub   = bar + 32 * (1 + grp);
    unsigned* root  = bar;
    unsigned* gflag = bar + 32 * (9 + grp);
    unsigned r = __hip_atomic_fetch_add(sub, 1u, __ATOMIC_RELAXED,
                                        __HIP_MEMORY_SCOPE_AGENT);
    if (r == 32u * gen - 1u) {          // last arriver of this group
      __hip_atomic_fetch_add(root, 1u, __ATOMIC_RELAXED,
                             __HIP_MEMORY_SCOPE_AGENT);
      while (__hip_atomic_load(root, __ATOMIC_RELAXED,
                               __HIP_MEMORY_SCOPE_AGENT) < 8u * gen)
        __builtin_amdgcn_s_sleep(2);
      __hip_atomic_store(gflag, gen, __ATOMIC_RELAXED,
                         __HIP_MEMORY_SCOPE_AGENT);
    }
    while (__hip_atomic_load(gflag, __ATOMIC_RELAXED,
                             __HIP_MEMORY_SCOPE_AGENT) < gen)
      __builtin_amdgcn_s_sleep(2);
    __builtin_amdgcn_fence(__ATOMIC_ACQUIRE, "agent");  // single buffer_inv
  }
  __syncthreads();
}

// ---------------- init: h0 bf16, Wl->bf16, bias = bx+bh (permuted), bar -----
__global__ void init_misc(const float* __restrict__ h_in, const float* __restrict__ Wl,
                          const float* __restrict__ bx, const float* __restrict__ bh,
                          ushort_t* __restrict__ hbf0, ushort_t* __restrict__ wlbf,
                          float* __restrict__ bias, unsigned* __restrict__ bar) {
  int i = blockIdx.x * blockDim.x + threadIdx.x;   // grid covers 131072 exactly
  hbf0[i] = f2bf(h_in[i]);
  wlbf[i] = f2bf(Wl[i]);
  if (i < NG) {
    int kg = i & 3, hc = i >> 2;
    bias[i] = bx[kg * HH + hc] + bh[kg * HH + hc];
  }
  if (i < 544) bar[i] = 0u;
}

// ---------------- x fp32 -> bf16 once (8 elems/thread) ----------------------
__global__ void xconv(const float* __restrict__ x, ushort_t* __restrict__ xbf) {
  size_t i = (size_t)(blockIdx.x * blockDim.x + threadIdx.x) * 8;
  *(uint4*)(xbf + i) = pack8(x + i);
}

// ------------- build WcombT[n][k] bf16, n = hc*4+kg, k = [x(128) | h(1024)] --
__global__ void build_wcombT(const float* __restrict__ Wx, const float* __restrict__ Wh,
                             ushort_t* __restrict__ wcombT) {
  __shared__ float tile[32][33];
  const int k0 = blockIdx.x * 32, hc0 = blockIdx.y * 32, kg = blockIdx.z;
  const int tid = threadIdx.x;
#pragma unroll
  for (int p = 0; p < 4; ++p) {
    int kk = (tid >> 5) + p * 8, hh = tid & 31;
    int k = k0 + kk, hc = hc0 + hh;
    float v = (k < VV) ? Wx[kg * VV * HH + k * HH + hc]
                       : Wh[kg * HH * HH + (k - VV) * HH + hc];
    tile[kk][hh] = v;
  }
  __syncthreads();
#pragma unroll
  for (int p = 0; p < 4; ++p) {
    int hh = (tid >> 5) + p * 8, kk = tid & 31;
    int n = (hc0 + hh) * 4 + kg;
    wcombT[n * KK + k0 + kk] = f2bf(tile[kk][hh]);
  }
}

// ---------------- persistent LSTM: all 256 timesteps, weights in VGPRs ------
// grid 256 (mb = blk&3 -> 32 batch rows, nb = blk>>2 -> 64 gate cols), 4 waves
__global__ __launch_bounds__(256, 1) void lstm_persist(
    const ushort_t* __restrict__ xbf, const ushort_t* __restrict__ wcombT,
    const float* __restrict__ bias, ushort_t* __restrict__ hping,
    unsigned* __restrict__ outs32, const float* __restrict__ c_in,
    float* __restrict__ hout, float* __restrict__ cout,
    unsigned* __restrict__ bar) {
  __shared__ __align__(16) ushort_t As[32 * 1024];   // 65,536 B (h panel only)

  const int tid = threadIdx.x;
  const int b0 = (blockIdx.x & 3) * 32;
  const int n0 = (blockIdx.x >> 2) * 64;
  const int grp = blockIdx.x & 7;
  const int wave = tid >> 6, lane = tid & 63;
  const int wm = wave >> 1, wn = wave & 1;
  const int c15 = lane & 15, q = lane >> 4;
  const int kg = lane & 3;
  const bool isg = (kg == 2);
  const int arow = wm * 16 + c15;                  // A-fragment row (0..31)
  const int rbase = b0 + wm * 16 + q * 4;
  const int hu0 = (n0 >> 2) + wn * 8 + (c15 >> 2); // + j*4

  // ---- one-time: B fragments into registers ----
  bf16x8 breg[36][2];
#pragma unroll
  for (int ks = 0; ks < 36; ++ks)
#pragma unroll
    for (int j = 0; j < 2; ++j)
      breg[ks][j] = *(const bf16x8*)(wcombT +
          (size_t)(n0 + wn * 32 + j * 16 + c15) * KK + ks * 32 + q * 8);

  float biasr[2];
#pragma unroll
  for (int j = 0; j < 2; ++j)
    biasr[j] = bias[n0 + wn * 32 + j * 16 + c15];

  float cr[2][4];
#pragma unroll
  for (int j = 0; j < 2; ++j)
#pragma unroll
    for (int r = 0; r < 4; ++r)
      cr[j][r] = c_in[(size_t)(rbase + r) * HH + hu0 + j * 4];

  const ushort_t* xlane = xbf + (size_t)(b0 + arow) * (TT * VV) + q * 8;

  // preload x fragments for t = 0
  bf16x8 xr[4];
#pragma unroll
  for (int ks = 0; ks < 4; ++ks)
    xr[ks] = *(const bf16x8*)(xlane + ks * 32);

  for (int t = 0; t < TT; ++t) {
    const ushort_t* hc_ = hping + (size_t)(t & 1) * BB * HH;
    ushort_t* hn_ = hping + (size_t)((t + 1) & 1) * BB * HH;

    // ---- stage h panel into LDS (swizzled) ----
#pragma unroll
    for (int i = 0; i < 16; ++i) {
      int idx = i * 256 + tid;
      int row = idx >> 7, ko = (idx & 127) * 8;
      *(uint4*)aswz(As, row, ko) =
          *(const uint4*)(hc_ + (size_t)(b0 + row) * HH + ko);
    }
    __syncthreads();

    // ---- MFMA K-loop: 4 independent accumulator chains ----
    f32x4 a0e = {0.f,0.f,0.f,0.f}, a0o = {0.f,0.f,0.f,0.f};
    f32x4 a1e = {0.f,0.f,0.f,0.f}, a1o = {0.f,0.f,0.f,0.f};
#pragma unroll
    for (int ks = 0; ks < 4; ks += 2) {       // x part from registers
      a0e = MFMA(xr[ks], breg[ks][0], a0e);
      a1e = MFMA(xr[ks], breg[ks][1], a1e);
      a0o = MFMA(xr[ks + 1], breg[ks + 1][0], a0o);
      a1o = MFMA(xr[ks + 1], breg[ks + 1][1], a1o);
    }
#pragma unroll
    for (int hs = 0; hs < 32; hs += 2) {      // h part from LDS
      bf16x8 af0 = *(const bf16x8*)aswz(As, arow, hs * 32 + q * 8);
      bf16x8 af1 = *(const bf16x8*)aswz(As, arow, (hs + 1) * 32 + q * 8);
      a0e = MFMA(af0, breg[4 + hs][0], a0e);
      a1e = MFMA(af0, breg[4 + hs][1], a1e);
      a0o = MFMA(af1, breg[5 + hs][0], a0o);
      a1o = MFMA(af1, breg[5 + hs][1], a1o);
    }
    f32x4 g0 = a0e + a0o, g1 = a1e + a1o;

    // ---- pointwise LSTM in registers (4 gates live in 4-lane groups) ----
    const bool last = (t == TT - 1);
#pragma unroll
    for (int j = 0; j < 2; ++j) {
      f32x4 gj = j ? g1 : g0;
#pragma unroll
      for (int r = 0; r < 4; ++r) {
        float pre = gj[r] + biasr[j];
        float sx = isg ? pre + pre : pre;
        float sg = 1.f / (1.f + expf(-sx));
        float a = isg ? sg + sg - 1.f : sg;     // own gate activation
        float fv = __shfl_xor(a, 1);
        float gv = __shfl_xor(a, 2);
        float ov = __shfl_xor(fv, 2);
        float cn = fv * cr[j][r] + a * gv;      // valid on kg==0 lanes
        cr[j][r] = cn;
        float hn = ov * tanhf(cn);
        unsigned hb = f2bf(hn), ob = f2bf(ov);
        unsigned hbp = (unsigned)__shfl_xor((int)hb, 4);
        unsigned obp = (unsigned)__shfl_xor((int)ob, 4);
        if ((lane & 7) == 0) {                  // kg==0 && even hu pair
          int b = rbase + r, hu = hu0 + j * 4;
          // h: device-coherent write-through (sc0 sc1) - no L2 flush needed
          __hip_atomic_store((unsigned*)(hn_ + (size_t)b * HH + hu),
                             hb | (hbp << 16), __ATOMIC_RELAXED,
                             __HIP_MEMORY_SCOPE_AGENT);
          outs32[(((size_t)b * TT + t) * HH + hu) >> 1] = ob | (obp << 16);
        }
        if (last && kg == 0) {
          int b = rbase + r, hu = hu0 + j * 4;
          hout[(size_t)b * HH + hu] = hn;
          cout[(size_t)b * HH + hu] = cn;
        }
      }
    }

    if (t < TT - 1) {
      // prefetch next x fragments; latency hides under the barrier wait
#pragma unroll
      for (int ks = 0; ks < 4; ++ks)
        xr[ks] = *(const bf16x8*)(xlane + (t + 1) * VV + ks * 32);
      gbar(bar, (unsigned)(t + 1), grp);
    }
  }
}

// ---------------- logits = outs(bf16) @ Wl^T + bl ---------------------------
// grid 512, 256 threads (waves 2x2), WG tile 64(M) x 128(N=V)
__global__ __launch_bounds__(256) void logits_gemm(
    const ushort_t* __restrict__ outs, const ushort_t* __restrict__ wlbf,
    const float* __restrict__ bl, float* __restrict__ out) {
  __shared__ __align__(16) ushort_t Asl[2][64][72];
  __shared__ __align__(16) ushort_t Bsl[2][128][72];
  const int tid = threadIdx.x;
  const int m0 = blockIdx.x * 64;
  const int wave = tid >> 6, lane = tid & 63;
  const int wm = wave >> 1, wn = wave & 1;
  const int ar = tid >> 2, ak = (tid & 3) * 16;
  const int br = tid >> 1, bk = (tid & 1) * 32;

  f32x4 acc[2][4];
#pragma unroll
  for (int i = 0; i < 2; ++i)
#pragma unroll
    for (int j = 0; j < 4; ++j) acc[i][j] = {0.f, 0.f, 0.f, 0.f};

  const ushort_t* pa = outs + (size_t)(m0 + ar) * HH + ak;
  uint4 av0 = *(const uint4*)pa, av1 = *(const uint4*)(pa + 8);
  const ushort_t* pb = wlbf + (size_t)br * HH + bk;
  uint4 bv0 = *(const uint4*)pb, bv1 = *(const uint4*)(pb + 8);
  uint4 bv2 = *(const uint4*)(pb + 16), bv3 = *(const uint4*)(pb + 24);

  int buf = 0;
  for (int s = 0; s < 16; ++s) {
    *(uint4*)&Asl[buf][ar][ak] = av0;
    *(uint4*)&Asl[buf][ar][ak + 8] = av1;
    *(uint4*)&Bsl[buf][br][bk] = bv0;
    *(uint4*)&Bsl[buf][br][bk + 8] = bv1;
    *(uint4*)&Bsl[buf][br][bk + 16] = bv2;
    *(uint4*)&Bsl[buf][br][bk + 24] = bv3;
    if (s < 15) {
      int k0 = (s + 1) * 64;
      const ushort_t* qa = outs + (size_t)(m0 + ar) * HH + k0 + ak;
      av0 = *(const uint4*)qa; av1 = *(const uint4*)(qa + 8);
      const ushort_t* qb = wlbf + (size_t)br * HH + k0 + bk;
      bv0 = *(const uint4*)qb; bv1 = *(const uint4*)(qb + 8);
      bv2 = *(const uint4*)(qb + 16); bv3 = *(const uint4*)(qb + 24);
    }
    __syncthreads();
#pragma unroll
    for (int kk = 0; kk < 64; kk += 32) {
      int koff = kk + (lane >> 4) * 8;
      bf16x8 a0 = *(const bf16x8*)&Asl[buf][wm * 32 + (lane & 15)][koff];
      bf16x8 a1 = *(const bf16x8*)&Asl[buf][wm * 32 + 16 + (lane & 15)][koff];
      bf16x8 b0 = *(const bf16x8*)&Bsl[buf][wn * 64 + (lane & 15)][koff];
      bf16x8 b1 = *(const bf16x8*)&Bsl[buf][wn * 64 + 16 + (lane & 15)][koff];
      bf16x8 b2 = *(const bf16x8*)&Bsl[buf][wn * 64 + 32 + (lane & 15)][koff];
      bf16x8 b3 = *(const bf16x8*)&Bsl[buf][wn * 64 + 48 + (lane & 15)][koff];
      acc[0][0] = MFMA(a0, b0, acc[0][0]);
      acc[0][1] = MFMA(a0, b1, acc[0][1]);
      acc[0][2] = MFMA(a0, b2, acc[0][2]);
      acc[0][3] = MFMA(a0, b3, acc[0][3]);
      acc[1][0] = MFMA(a1, b0, acc[1][0]);
      acc[1][1] = MFMA(a1, b1, acc[1][1]);
      acc[1][2] = MFMA(a1, b2, acc[1][2]);
      acc[1][3] = MFMA(a1, b3, acc[1][3]);
    }
    buf ^= 1;
  }
#pragma unroll
  for (int i = 0; i < 2; ++i)
#pragma unroll
    for (int j = 0; j < 4; ++j)
#pragma unroll
      for (int r = 0; r < 4; ++r) {
        int m = m0 + wm * 32 + i * 16 + (lane >> 4) * 4 + r;
        int v = wn * 64 + j * 16 + (lane & 15);
        out[(size_t)m * VV + v] = acc[i][j][r] + bl[v];
      }
}

// ----------------------------------------------------------------------------
extern "C" void kernel_launch(void* const* d_in, const int* in_sizes, int n_in,
                              void* d_out, int out_size, void* d_ws, size_t ws_size,
                              hipStream_t stream) {
  const float* x    = (const float*)d_in[0];
  const float* h_in = (const float*)d_in[1];
  const float* c_in = (const float*)d_in[2];
  const float* Wx   = (const float*)d_in[3];
  const float* Wh   = (const float*)d_in[4];
  const float* bx   = (const float*)d_in[5];
  const float* bh   = (const float*)d_in[6];
  const float* Wl   = (const float*)d_in[7];
  const float* bl   = (const float*)d_in[8];

  char* ws = (char*)d_ws;
  size_t off = 0;
  ushort_t* wcombT = (ushort_t*)(ws + off); off += (size_t)NG * KK * 2;        // 9.4 MB
  ushort_t* outs   = (ushort_t*)(ws + off); off += (size_t)BB * TT * HH * 2;   // 67 MB
  ushort_t* hbf    = (ushort_t*)(ws + off); off += (size_t)2 * BB * HH * 2;    // ping-pong
  float*    bias   = (float*)(ws + off);    off += (size_t)NG * 4;
  ushort_t* wlbf   = (ushort_t*)(ws + off); off += (size_t)VV * HH * 2;
  off = (off + 127) & ~(size_t)127;
  unsigned* bar    = (unsigned*)(ws + off); off += 544 * 4;

  float* out  = (float*)d_out;
  float* hout = out + (size_t)BB * TT * VV;
  float* cout = hout + (size_t)BB * HH;
  // xbf (8.4 MB) aliases the logits region of d_out (16.8 MB): read only by
  // lstm_persist, overwritten afterwards by logits_gemm. No ws growth.
  ushort_t* xbf = (ushort_t*)d_out;

  init_misc<<<dim3(512), dim3(256), 0, stream>>>(h_in, Wl, bx, bh,
                                                 hbf, wlbf, bias, bar);
  xconv<<<dim3(2048), dim3(256), 0, stream>>>(x, xbf);
  build_wcombT<<<dim3(36, 32, 4), dim3(256), 0, stream>>>(Wx, Wh, wcombT);

  {
    unsigned* outs32 = (unsigned*)outs;
    void* kargs[] = {(void*)&xbf, (void*)&wcombT, (void*)&bias, (void*)&hbf,
                     (void*)&outs32, (void*)&c_in, (void*)&hout, (void*)&cout,
                     (void*)&bar};
    hipError_t ce = hipLaunchCooperativeKernel((const void*)lstm_persist,
                                               dim3(256), dim3(256), kargs, 0,
                                               stream);
    if (ce != hipSuccess) {
      (void)hipGetLastError();  // clear sticky error; fall back to plain launch
      lstm_persist<<<dim3(256), dim3(256), 0, stream>>>(
          xbf, wcombT, bias, hbf, (unsigned*)outs, c_in, hout, cout, bar);
    }
  }

  logits_gemm<<<dim3(512), dim3(256), 0, stream>>>(outs, wlbf, bl, out);
}